// Round 4
// baseline (818.652 us; speedup 1.0000x reference)
//
#include <hip/hip_runtime.h>
#include <hip/hip_fp16.h>

#define NN 200000
#define NE 6400000
#define FIN 512
#define HID 16
#define NC 7
#define NB 782        // ceil(NN/256); also bucket count (256 nodes/bucket)
#define K  782        // bucket = dst >> 8
#define CH 8192       // edges per block (count + fill)
#define EB 782        // ceil(NE/CH)
#define KC 32
#define WMAX 10240    // per-bucket edge cap for LDS sort (mean 8184, sigma ~90 -> 22 sigma margin)

// ---------- fp16 helpers ----------
__device__ __forceinline__ unsigned f2h(float a, float b) {
    __half2 h = __floats2half2_rn(a, b);
    return __builtin_bit_cast(unsigned, h);
}
__device__ __forceinline__ float2 h2f(unsigned u) {
    return __half22float2(__builtin_bit_cast(__half2, u));
}

// ============ bucket count: LDS histogram of dst>>8 (int4-vectorized reads) ============

__global__ __launch_bounds__(256) void k_bcount(const int* __restrict__ dst, int* __restrict__ bucket_total) {
    __shared__ int hist[K];
    int tid = threadIdx.x;
    long e0 = (long)blockIdx.x * CH;
    int cnt = (int)min((long)CH, (long)NE - e0);   // always %4==0
    for (int i = tid; i < K; i += 256) hist[i] = 0;
    __syncthreads();
    const int4* d4 = (const int4*)(dst + e0);
    int n4 = cnt >> 2;
    for (int i = tid; i < n4; i += 256) {
        int4 d = d4[i];
        atomicAdd(&hist[d.x >> 8], 1);
        atomicAdd(&hist[d.y >> 8], 1);
        atomicAdd(&hist[d.z >> 8], 1);
        atomicAdd(&hist[d.w >> 8], 1);
    }
    __syncthreads();
    for (int b = tid; b < K; b += 256) {
        int h = hist[b];
        if (h) atomicAdd(&bucket_total[b], h);
    }
}

// ============ bucket fill: per-block scan of bucket_total (kills k_bscan) + LDS bin-sort stage
//              -> COALESCED run writes. Block 0 publishes bucket_base. ============

__global__ __launch_bounds__(256) void k_bfill(const int* __restrict__ src, const int* __restrict__ dst,
                                               const int* __restrict__ bucket_total,
                                               int* __restrict__ bucket_cursor,     // zero-initialized
                                               int* __restrict__ bucket_base,
                                               unsigned int* __restrict__ bwords) {
    __shared__ int hist[K];
    __shared__ int ofs0[K];
    __shared__ int gb2[K];
    __shared__ int base_l[K];
    __shared__ int ptmp[256];
    __shared__ unsigned long long stage[CH];
    int tid = threadIdx.x;
    long e0 = (long)blockIdx.x * CH;
    int cnt = (int)min((long)CH, (long)NE - e0);   // %4==0

    for (int i = tid; i < K; i += 256) hist[i] = 0;
    __syncthreads();
    const int4* d4 = (const int4*)(dst + e0);
    const int4* s4 = (const int4*)(src + e0);
    int n4 = cnt >> 2;
    for (int i = tid; i < n4; i += 256) {
        int4 d = d4[i];
        atomicAdd(&hist[d.x >> 8], 1);
        atomicAdd(&hist[d.y >> 8], 1);
        atomicAdd(&hist[d.z >> 8], 1);
        atomicAdd(&hist[d.w >> 8], 1);
    }
    __syncthreads();

    int b0 = tid * 4;
    // ---- scan #1: local hist -> ofs0 (block-local run starts) ----
    {
        int h0 = (b0 + 0 < K) ? hist[b0 + 0] : 0;
        int h1 = (b0 + 1 < K) ? hist[b0 + 1] : 0;
        int h2 = (b0 + 2 < K) ? hist[b0 + 2] : 0;
        int h3 = (b0 + 3 < K) ? hist[b0 + 3] : 0;
        int s = h0 + h1 + h2 + h3;
        ptmp[tid] = s;
        __syncthreads();
        #pragma unroll
        for (int off = 1; off < 256; off <<= 1) {
            int t = (tid >= off) ? ptmp[tid - off] : 0;
            __syncthreads();
            ptmp[tid] += t;
            __syncthreads();
        }
        int run = ptmp[tid] - s;
        if (b0 + 0 < K) { ofs0[b0 + 0] = run; run += h0; }
        if (b0 + 1 < K) { ofs0[b0 + 1] = run; run += h1; }
        if (b0 + 2 < K) { ofs0[b0 + 2] = run; run += h2; }
        if (b0 + 3 < K) { ofs0[b0 + 3] = run; run += h3; }
    }
    __syncthreads();
    // ---- scan #2: global bucket_total -> base_l (bucket bases; replaces k_bscan) ----
    {
        int t0 = (b0 + 0 < K) ? bucket_total[b0 + 0] : 0;
        int t1 = (b0 + 1 < K) ? bucket_total[b0 + 1] : 0;
        int t2 = (b0 + 2 < K) ? bucket_total[b0 + 2] : 0;
        int t3 = (b0 + 3 < K) ? bucket_total[b0 + 3] : 0;
        int s = t0 + t1 + t2 + t3;
        ptmp[tid] = s;
        __syncthreads();
        #pragma unroll
        for (int off = 1; off < 256; off <<= 1) {
            int t = (tid >= off) ? ptmp[tid - off] : 0;
            __syncthreads();
            ptmp[tid] += t;
            __syncthreads();
        }
        int run = ptmp[tid] - s;
        if (b0 + 0 < K) { base_l[b0 + 0] = run; run += t0; }
        if (b0 + 1 < K) { base_l[b0 + 1] = run; run += t1; }
        if (b0 + 2 < K) { base_l[b0 + 2] = run; run += t2; }
        if (b0 + 3 < K) { base_l[b0 + 3] = run; run += t3; }
    }
    __syncthreads();

    // claim bucket-relative space; absolute dst = base_l + g
    for (int b = tid; b < K; b += 256) {
        int h = hist[b];
        int g = h ? atomicAdd(&bucket_cursor[b], h) : 0;
        gb2[b] = base_l[b] + g - ofs0[b];
    }
    __syncthreads();
    for (int b = tid; b < K; b += 256) hist[b] = 0;
    __syncthreads();

    for (int i = tid; i < n4; i += 256) {
        int4 d = d4[i];
        int4 sv = s4[i];
        {
            int bin = d.x >> 8;
            int r = atomicAdd(&hist[bin], 1);
            stage[ofs0[bin] + r] = ((unsigned long long)(unsigned int)d.x << 32)
                | (((unsigned int)(d.x & 255) << 24) | (unsigned int)sv.x);
        }
        {
            int bin = d.y >> 8;
            int r = atomicAdd(&hist[bin], 1);
            stage[ofs0[bin] + r] = ((unsigned long long)(unsigned int)d.y << 32)
                | (((unsigned int)(d.y & 255) << 24) | (unsigned int)sv.y);
        }
        {
            int bin = d.z >> 8;
            int r = atomicAdd(&hist[bin], 1);
            stage[ofs0[bin] + r] = ((unsigned long long)(unsigned int)d.z << 32)
                | (((unsigned int)(d.z & 255) << 24) | (unsigned int)sv.z);
        }
        {
            int bin = d.w >> 8;
            int r = atomicAdd(&hist[bin], 1);
            stage[ofs0[bin] + r] = ((unsigned long long)(unsigned int)d.w << 32)
                | (((unsigned int)(d.w & 255) << 24) | (unsigned int)sv.w);
        }
    }
    __syncthreads();
    // coalesced: consecutive i -> consecutive bwords addresses within each run
    for (int i = tid; i < cnt; i += 256) {
        unsigned long long p = stage[i];
        int bin = (int)(p >> 40);
        bwords[gb2[bin] + i] = (unsigned int)p;
    }
    // publish bases once for downstream kernels
    if (blockIdx.x == 0) {
        for (int i = tid; i < K; i += 256) bucket_base[i] = base_l[i];
        if (tid == 0) bucket_base[K] = NE;
    }
}

// ============ gemm1: deg preamble (hidden under 410MB stream) + h1s = fp16((x@W1)*dinv) ============

__global__ __launch_bounds__(256) void k_gemm1(const float* __restrict__ x, const float* __restrict__ W1,
                                               const unsigned int* __restrict__ bwords,
                                               const int* __restrict__ bucket_base,
                                               __half* __restrict__ h1s) {
    __shared__ float xs[KC][257];
    __shared__ int cntd[256];
    const int tid = threadIdx.x;
    const int b = blockIdx.x;                 // block == bucket
    const int row0 = b * 256;
    const int row = row0 + tid;

    cntd[tid] = 0;
    __syncthreads();
    {
        int p0 = bucket_base[b];
        int m = min(bucket_base[b + 1] - p0, WMAX);
        for (int i = tid; i < m; i += 256) atomicAdd(&cntd[bwords[p0 + i] >> 24], 1);
    }
    __syncthreads();
    float dv = rsqrtf((float)(cntd[tid] + 1));   // +1 self-loop; identical formula in aggs

    float acc[HID];
    #pragma unroll
    for (int c = 0; c < HID; ++c) acc[c] = 0.f;

    for (int k0 = 0; k0 < FIN; k0 += KC) {
        __syncthreads();
        #pragma unroll
        for (int j = 0; j < 8; ++j) {
            int f = tid + 256 * j;
            int r = f >> 3;
            int kq = f & 7;
            int gr = row0 + r;
            float4 v = make_float4(0.f, 0.f, 0.f, 0.f);
            if (gr < NN) v = *(const float4*)(x + (size_t)gr * FIN + k0 + kq * 4);
            xs[kq * 4 + 0][r] = v.x;
            xs[kq * 4 + 1][r] = v.y;
            xs[kq * 4 + 2][r] = v.z;
            xs[kq * 4 + 3][r] = v.w;
        }
        __syncthreads();
        #pragma unroll 4
        for (int k = 0; k < KC; ++k) {
            float xv = xs[k][tid];
            const float4* w = (const float4*)(W1 + (size_t)(k0 + k) * HID);
            float4 w0 = w[0], w1 = w[1], w2 = w[2], w3 = w[3];
            acc[0]  = fmaf(xv, w0.x, acc[0]);  acc[1]  = fmaf(xv, w0.y, acc[1]);
            acc[2]  = fmaf(xv, w0.z, acc[2]);  acc[3]  = fmaf(xv, w0.w, acc[3]);
            acc[4]  = fmaf(xv, w1.x, acc[4]);  acc[5]  = fmaf(xv, w1.y, acc[5]);
            acc[6]  = fmaf(xv, w1.z, acc[6]);  acc[7]  = fmaf(xv, w1.w, acc[7]);
            acc[8]  = fmaf(xv, w2.x, acc[8]);  acc[9]  = fmaf(xv, w2.y, acc[9]);
            acc[10] = fmaf(xv, w2.z, acc[10]); acc[11] = fmaf(xv, w2.w, acc[11]);
            acc[12] = fmaf(xv, w3.x, acc[12]); acc[13] = fmaf(xv, w3.y, acc[13]);
            acc[14] = fmaf(xv, w3.z, acc[14]); acc[15] = fmaf(xv, w3.w, acc[15]);
        }
    }
    if (row < NN) {
        uint4 u0, u1;
        u0.x = f2h(acc[0]  * dv, acc[1]  * dv); u0.y = f2h(acc[2]  * dv, acc[3]  * dv);
        u0.z = f2h(acc[4]  * dv, acc[5]  * dv); u0.w = f2h(acc[6]  * dv, acc[7]  * dv);
        u1.x = f2h(acc[8]  * dv, acc[9]  * dv); u1.y = f2h(acc[10] * dv, acc[11] * dv);
        u1.z = f2h(acc[12] * dv, acc[13] * dv); u1.w = f2h(acc[14] * dv, acc[15] * dv);
        uint4* o = (uint4*)(h1s + (size_t)row * HID);
        o[0] = u0; o[1] = u1;
    }
}

// ============ agg1: fused in-LDS bucket sort + 4-lane/node gather + epilogue ============
// 1024 threads: sort preamble overlaps gather latency across blocks (r1-proven ~free);
// edge indices come from LDS, no node_base / sorted write-back / index re-read.

__device__ __forceinline__ void accrow16(float* A, uint4 a, uint4 b) {
    float2 f;
    f = h2f(a.x); A[0]  += f.x; A[1]  += f.y;
    f = h2f(a.y); A[2]  += f.x; A[3]  += f.y;
    f = h2f(a.z); A[4]  += f.x; A[5]  += f.y;
    f = h2f(a.w); A[6]  += f.x; A[7]  += f.y;
    f = h2f(b.x); A[8]  += f.x; A[9]  += f.y;
    f = h2f(b.y); A[10] += f.x; A[11] += f.y;
    f = h2f(b.z); A[12] += f.x; A[13] += f.y;
    f = h2f(b.w); A[14] += f.x; A[15] += f.y;
}

__global__ __launch_bounds__(1024) void k_agg1(const unsigned int* __restrict__ bwords,
                                               const int* __restrict__ bucket_base,
                                               const __half* __restrict__ h1s,
                                               const float* __restrict__ b1, const float* __restrict__ W2,
                                               __half* __restrict__ h2s) {
    __shared__ int cnt[256];
    __shared__ int st[256];
    __shared__ unsigned int ew[WMAX];
    int b = blockIdx.x;
    int tid = threadIdx.x;
    int p0 = bucket_base[b];
    int m = min(bucket_base[b + 1] - p0, WMAX);

    if (tid < 256) cnt[tid] = 0;
    __syncthreads();
    for (int i = tid; i < m; i += 1024) atomicAdd(&cnt[bwords[p0 + i] >> 24], 1);
    __syncthreads();
    if (tid < 256) st[tid] = cnt[tid];
    __syncthreads();
    #pragma unroll
    for (int off = 1; off < 256; off <<= 1) {
        int t = 0;
        if (tid < 256 && tid >= off) t = st[tid - off];
        __syncthreads();
        if (tid < 256) st[tid] += t;
        __syncthreads();
    }
    if (tid < 256) { st[tid] -= cnt[tid]; cnt[tid] = 0; }   // st = exclusive start
    __syncthreads();
    for (int i = tid; i < m; i += 1024) {
        unsigned int w = bwords[p0 + i];        // L2-warm re-read
        int loc = w >> 24;
        int r = atomicAdd(&cnt[loc], 1);
        ew[st[loc] + r] = w & 0xFFFFFFu;        // pure src id, node-grouped
    }
    __syncthreads();

    int ln = tid >> 2;
    int sub = tid & 3;
    int n = (b << 8) + ln;
    int v = cnt[ln];
    int e0 = st[ln];
    int e1 = e0 + v;
    float acc[HID];
    #pragma unroll
    for (int c = 0; c < HID; ++c) acc[c] = 0.f;

    int j = e0 + sub;
    for (; j + 4 < e1; j += 8) {             // 4 rows in flight per lane
        unsigned s0 = ew[j], s1 = ew[j + 4];
        const uint4* P0 = (const uint4*)(h1s + (size_t)s0 * HID);
        const uint4* P1 = (const uint4*)(h1s + (size_t)s1 * HID);
        uint4 a0 = P0[0], c0 = P0[1], a1 = P1[0], c1 = P1[1];
        accrow16(acc, a0, c0);
        accrow16(acc, a1, c1);
    }
    if (j < e1) {
        unsigned s0 = ew[j];
        const uint4* P0 = (const uint4*)(h1s + (size_t)s0 * HID);
        uint4 a0 = P0[0], c0 = P0[1];
        accrow16(acc, a0, c0);
    }
    #pragma unroll
    for (int c = 0; c < HID; ++c) {
        acc[c] += __shfl_xor(acc[c], 1);
        acc[c] += __shfl_xor(acc[c], 2);
    }
    if (sub == 0 && n < NN) {
        {   // self-loop from own (prescaled) row
            const uint4* q = (const uint4*)(h1s + (size_t)n * HID);
            uint4 a = q[0], bb = q[1];
            accrow16(acc, a, bb);
        }
        float dv = rsqrtf((float)(v + 1));      // identical to gemm1's dinv
        float h[HID];
        #pragma unroll
        for (int c = 0; c < HID; ++c) h[c] = fmaxf(fmaf(dv, acc[c], b1[c]), 0.f);
        float z[8];
        #pragma unroll
        for (int jj = 0; jj < NC; ++jj) {
            float t2 = 0.f;
            #pragma unroll
            for (int c = 0; c < HID; ++c) t2 = fmaf(h[c], W2[c * NC + jj], t2);
            z[jj] = t2 * dv;
        }
        z[7] = 0.f;
        uint4 u;
        u.x = f2h(z[0], z[1]); u.y = f2h(z[2], z[3]); u.z = f2h(z[4], z[5]); u.w = f2h(z[6], z[7]);
        *(uint4*)(h2s + (size_t)n * 8) = u;
    }
}

// ============ agg2: same fused structure, 16B rows, fp32 out ============

__global__ __launch_bounds__(1024) void k_agg2(const unsigned int* __restrict__ bwords,
                                               const int* __restrict__ bucket_base,
                                               const __half* __restrict__ h2s,
                                               const float* __restrict__ b2, float* __restrict__ out) {
    __shared__ int cnt[256];
    __shared__ int st[256];
    __shared__ unsigned int ew[WMAX];
    int b = blockIdx.x;
    int tid = threadIdx.x;
    int p0 = bucket_base[b];
    int m = min(bucket_base[b + 1] - p0, WMAX);

    if (tid < 256) cnt[tid] = 0;
    __syncthreads();
    for (int i = tid; i < m; i += 1024) atomicAdd(&cnt[bwords[p0 + i] >> 24], 1);
    __syncthreads();
    if (tid < 256) st[tid] = cnt[tid];
    __syncthreads();
    #pragma unroll
    for (int off = 1; off < 256; off <<= 1) {
        int t = 0;
        if (tid < 256 && tid >= off) t = st[tid - off];
        __syncthreads();
        if (tid < 256) st[tid] += t;
        __syncthreads();
    }
    if (tid < 256) { st[tid] -= cnt[tid]; cnt[tid] = 0; }
    __syncthreads();
    for (int i = tid; i < m; i += 1024) {
        unsigned int w = bwords[p0 + i];
        int loc = w >> 24;
        int r = atomicAdd(&cnt[loc], 1);
        ew[st[loc] + r] = w & 0xFFFFFFu;
    }
    __syncthreads();

    int ln = tid >> 2;
    int sub = tid & 3;
    int n = (b << 8) + ln;
    int v = cnt[ln];
    int e0 = st[ln];
    int e1 = e0 + v;
    float A[8];
    #pragma unroll
    for (int c = 0; c < 8; ++c) A[c] = 0.f;

    int j = e0 + sub;
    for (; j + 4 < e1; j += 8) {
        unsigned s0 = ew[j], s1 = ew[j + 4];
        uint4 a = *(const uint4*)(h2s + (size_t)s0 * 8);
        uint4 c = *(const uint4*)(h2s + (size_t)s1 * 8);
        float2 f;
        f = h2f(a.x); A[0] += f.x; A[1] += f.y;
        f = h2f(a.y); A[2] += f.x; A[3] += f.y;
        f = h2f(a.z); A[4] += f.x; A[5] += f.y;
        f = h2f(a.w); A[6] += f.x;
        f = h2f(c.x); A[0] += f.x; A[1] += f.y;
        f = h2f(c.y); A[2] += f.x; A[3] += f.y;
        f = h2f(c.z); A[4] += f.x; A[5] += f.y;
        f = h2f(c.w); A[6] += f.x;
    }
    if (j < e1) {
        unsigned s0 = ew[j];
        uint4 a = *(const uint4*)(h2s + (size_t)s0 * 8);
        float2 f;
        f = h2f(a.x); A[0] += f.x; A[1] += f.y;
        f = h2f(a.y); A[2] += f.x; A[3] += f.y;
        f = h2f(a.z); A[4] += f.x; A[5] += f.y;
        f = h2f(a.w); A[6] += f.x;
    }
    #pragma unroll
    for (int c = 0; c < NC; ++c) {
        A[c] += __shfl_xor(A[c], 1);
        A[c] += __shfl_xor(A[c], 2);
    }
    if (sub == 0 && n < NN) {
        {   // self-loop
            uint4 a = *(const uint4*)(h2s + (size_t)n * 8);
            float2 f;
            f = h2f(a.x); A[0] += f.x; A[1] += f.y;
            f = h2f(a.y); A[2] += f.x; A[3] += f.y;
            f = h2f(a.z); A[4] += f.x; A[5] += f.y;
            f = h2f(a.w); A[6] += f.x;
        }
        float dv = rsqrtf((float)(v + 1));
        #pragma unroll
        for (int jj = 0; jj < NC; ++jj) out[(size_t)n * NC + jj] = fmaf(dv, A[jj], b2[jj]);
    }
}

// ============ launch ============

extern "C" void kernel_launch(void* const* d_in, const int* in_sizes, int n_in,
                              void* d_out, int out_size, void* d_ws, size_t ws_size,
                              hipStream_t stream) {
    const float* x  = (const float*)d_in[0];
    const int*   ei = (const int*)d_in[1];
    const float* W1 = (const float*)d_in[2];
    const float* b1 = (const float*)d_in[3];
    const float* W2 = (const float*)d_in[4];
    const float* b2 = (const float*)d_in[5];
    const int* src = ei;
    const int* dst = ei + NE;
    float* out = (float*)d_out;

    char* ws = (char*)d_ws;
    size_t o = 0;
    auto alloc = [&](size_t bytes) {
        char* p = ws + o;
        o = (o + bytes + 255) & ~(size_t)255;
        return p;
    };
    int*   btc           = (int*)alloc((size_t)2 * (K + 1) * 4);  // total + cursor, one memset
    int*   bucket_total  = btc;
    int*   bucket_cursor = btc + (K + 1);
    int*   bucket_base   = (int*)alloc((size_t)(K + 1) * 4);
    unsigned int* bwords = (unsigned int*)alloc((size_t)NE * 4);
    __half* h1s  = (__half*)alloc((size_t)NN * HID * 2);
    __half* h2s  = (__half*)alloc((size_t)NN * 8 * 2);

    hipMemsetAsync(btc, 0, (size_t)2 * (K + 1) * 4, stream);
    k_bcount<<<EB, 256, 0, stream>>>(dst, bucket_total);
    k_bfill <<<EB, 256, 0, stream>>>(src, dst, bucket_total, bucket_cursor, bucket_base, bwords);
    k_gemm1 <<<NB, 256, 0, stream>>>(x, W1, bwords, bucket_base, h1s);
    k_agg1  <<<K, 1024, 0, stream>>>(bwords, bucket_base, h1s, b1, W2, h2s);
    k_agg2  <<<K, 1024, 0, stream>>>(bwords, bucket_base, h2s, b2, out);
}

// Round 7
// 781.341 us; speedup vs baseline: 1.0478x; 1.0478x over previous
//
#include <hip/hip_runtime.h>
#include <hip/hip_fp16.h>

#define NN 200000
#define NE 6400000
#define FIN 512
#define HID 16
#define NC 7
#define NB 782        // ceil(NN/256); also bucket count (256 nodes/bucket)
#define K  782        // bucket = dst >> 8
#define CH 8192       // edges per block (fill)
#define EB 782        // ceil(NE/CH)
#define KC 32
#define WMAX 10240    // per-bucket region stride (mean 8184, sigma ~90 -> 22 sigma margin)

// ---------- fp16 helpers ----------
__device__ __forceinline__ unsigned f2h(float a, float b) {
    __half2 h = __floats2half2_rn(a, b);
    return __builtin_bit_cast(unsigned, h);
}
__device__ __forceinline__ float2 h2f(unsigned u) {
    return __half22float2(__builtin_bit_cast(__half2, u));
}

// ============ bucket fill: fixed WMAX-strided bucket regions (kills k_bcount + global scan).
// Per-block LDS hist -> local scan -> claim per-bucket space via global cursor atomics ->
// LDS bin-sort stage -> COALESCED run writes into bwords[b*WMAX ...]. ============

__global__ __launch_bounds__(256) void k_bfill(const int* __restrict__ src, const int* __restrict__ dst,
                                               int* __restrict__ bucket_cursor,     // zero-initialized
                                               unsigned int* __restrict__ bwords) {
    __shared__ int hist[K];
    __shared__ int ofs0[K];
    __shared__ int gb2[K];
    __shared__ int ptmp[256];
    __shared__ unsigned long long stage[CH];
    int tid = threadIdx.x;
    long e0 = (long)blockIdx.x * CH;
    int cnt = (int)min((long)CH, (long)NE - e0);   // %4==0

    for (int i = tid; i < K; i += 256) hist[i] = 0;
    __syncthreads();
    const int4* d4 = (const int4*)(dst + e0);
    const int4* s4 = (const int4*)(src + e0);
    int n4 = cnt >> 2;
    for (int i = tid; i < n4; i += 256) {
        int4 d = d4[i];
        atomicAdd(&hist[d.x >> 8], 1);
        atomicAdd(&hist[d.y >> 8], 1);
        atomicAdd(&hist[d.z >> 8], 1);
        atomicAdd(&hist[d.w >> 8], 1);
    }
    __syncthreads();

    int b0 = tid * 4;
    // ---- scan: local hist -> ofs0 (block-local run starts) ----
    {
        int h0 = (b0 + 0 < K) ? hist[b0 + 0] : 0;
        int h1 = (b0 + 1 < K) ? hist[b0 + 1] : 0;
        int h2 = (b0 + 2 < K) ? hist[b0 + 2] : 0;
        int h3 = (b0 + 3 < K) ? hist[b0 + 3] : 0;
        int s = h0 + h1 + h2 + h3;
        ptmp[tid] = s;
        __syncthreads();
        #pragma unroll
        for (int off = 1; off < 256; off <<= 1) {
            int t = (tid >= off) ? ptmp[tid - off] : 0;
            __syncthreads();
            ptmp[tid] += t;
            __syncthreads();
        }
        int run = ptmp[tid] - s;
        if (b0 + 0 < K) { ofs0[b0 + 0] = run; run += h0; }
        if (b0 + 1 < K) { ofs0[b0 + 1] = run; run += h1; }
        if (b0 + 2 < K) { ofs0[b0 + 2] = run; run += h2; }
        if (b0 + 3 < K) { ofs0[b0 + 3] = run; run += h3; }
    }
    __syncthreads();

    // claim bucket-relative space; absolute dst = b*WMAX + g
    for (int b = tid; b < K; b += 256) {
        int h = hist[b];
        int g = h ? atomicAdd(&bucket_cursor[b], h) : 0;
        gb2[b] = b * WMAX + g - ofs0[b];
    }
    __syncthreads();
    for (int b = tid; b < K; b += 256) hist[b] = 0;
    __syncthreads();

    for (int i = tid; i < n4; i += 256) {
        int4 d = d4[i];
        int4 sv = s4[i];
        {
            int bin = d.x >> 8;
            int r = atomicAdd(&hist[bin], 1);
            stage[ofs0[bin] + r] = ((unsigned long long)(unsigned int)d.x << 32)
                | (((unsigned int)(d.x & 255) << 24) | (unsigned int)sv.x);
        }
        {
            int bin = d.y >> 8;
            int r = atomicAdd(&hist[bin], 1);
            stage[ofs0[bin] + r] = ((unsigned long long)(unsigned int)d.y << 32)
                | (((unsigned int)(d.y & 255) << 24) | (unsigned int)sv.y);
        }
        {
            int bin = d.z >> 8;
            int r = atomicAdd(&hist[bin], 1);
            stage[ofs0[bin] + r] = ((unsigned long long)(unsigned int)d.z << 32)
                | (((unsigned int)(d.z & 255) << 24) | (unsigned int)sv.z);
        }
        {
            int bin = d.w >> 8;
            int r = atomicAdd(&hist[bin], 1);
            stage[ofs0[bin] + r] = ((unsigned long long)(unsigned int)d.w << 32)
                | (((unsigned int)(d.w & 255) << 24) | (unsigned int)sv.w);
        }
    }
    __syncthreads();
    // coalesced: consecutive i -> consecutive bwords addresses within each run
    for (int i = tid; i < cnt; i += 256) {
        unsigned long long p = stage[i];
        int bin = (int)(p >> 40);
        int off = gb2[bin] + i;
        if (off < (bin + 1) * WMAX) bwords[off] = (unsigned int)p;   // overflow guard (never in practice)
    }
}

// ============ gemm1: deg preamble (hidden under 410MB stream) + h1s = fp16((x@W1)*dinv) ============

__global__ __launch_bounds__(256) void k_gemm1(const float* __restrict__ x, const float* __restrict__ W1,
                                               const unsigned int* __restrict__ bwords,
                                               const int* __restrict__ bucket_cursor,
                                               __half* __restrict__ h1s) {
    __shared__ float xs[KC][257];
    __shared__ int cntd[256];
    const int tid = threadIdx.x;
    const int b = blockIdx.x;                 // block == bucket
    const int row0 = b * 256;
    const int row = row0 + tid;

    cntd[tid] = 0;
    __syncthreads();
    {
        int p0 = b * WMAX;
        int m = min(bucket_cursor[b], WMAX);
        for (int i = tid; i < m; i += 256) atomicAdd(&cntd[bwords[p0 + i] >> 24], 1);
    }
    __syncthreads();
    float dv = rsqrtf((float)(cntd[tid] + 1));   // +1 self-loop; identical formula in aggs

    float acc[HID];
    #pragma unroll
    for (int c = 0; c < HID; ++c) acc[c] = 0.f;

    for (int k0 = 0; k0 < FIN; k0 += KC) {
        __syncthreads();
        #pragma unroll
        for (int j = 0; j < 8; ++j) {
            int f = tid + 256 * j;
            int r = f >> 3;
            int kq = f & 7;
            int gr = row0 + r;
            float4 v = make_float4(0.f, 0.f, 0.f, 0.f);
            if (gr < NN) v = *(const float4*)(x + (size_t)gr * FIN + k0 + kq * 4);
            xs[kq * 4 + 0][r] = v.x;
            xs[kq * 4 + 1][r] = v.y;
            xs[kq * 4 + 2][r] = v.z;
            xs[kq * 4 + 3][r] = v.w;
        }
        __syncthreads();
        #pragma unroll 4
        for (int k = 0; k < KC; ++k) {
            float xv = xs[k][tid];
            const float4* w = (const float4*)(W1 + (size_t)(k0 + k) * HID);
            float4 w0 = w[0], w1 = w[1], w2 = w[2], w3 = w[3];
            acc[0]  = fmaf(xv, w0.x, acc[0]);  acc[1]  = fmaf(xv, w0.y, acc[1]);
            acc[2]  = fmaf(xv, w0.z, acc[2]);  acc[3]  = fmaf(xv, w0.w, acc[3]);
            acc[4]  = fmaf(xv, w1.x, acc[4]);  acc[5]  = fmaf(xv, w1.y, acc[5]);
            acc[6]  = fmaf(xv, w1.z, acc[6]);  acc[7]  = fmaf(xv, w1.w, acc[7]);
            acc[8]  = fmaf(xv, w2.x, acc[8]);  acc[9]  = fmaf(xv, w2.y, acc[9]);
            acc[10] = fmaf(xv, w2.z, acc[10]); acc[11] = fmaf(xv, w2.w, acc[11]);
            acc[12] = fmaf(xv, w3.x, acc[12]); acc[13] = fmaf(xv, w3.y, acc[13]);
            acc[14] = fmaf(xv, w3.z, acc[14]); acc[15] = fmaf(xv, w3.w, acc[15]);
        }
    }
    if (row < NN) {
        uint4 u0, u1;
        u0.x = f2h(acc[0]  * dv, acc[1]  * dv); u0.y = f2h(acc[2]  * dv, acc[3]  * dv);
        u0.z = f2h(acc[4]  * dv, acc[5]  * dv); u0.w = f2h(acc[6]  * dv, acc[7]  * dv);
        u1.x = f2h(acc[8]  * dv, acc[9]  * dv); u1.y = f2h(acc[10] * dv, acc[11] * dv);
        u1.z = f2h(acc[12] * dv, acc[13] * dv); u1.w = f2h(acc[14] * dv, acc[15] * dv);
        uint4* o = (uint4*)(h1s + (size_t)row * HID);
        o[0] = u0; o[1] = u1;
    }
}

// ============ agg1: fused in-LDS bucket sort + 4-lane/node gather (UNROLL-4) + epilogue ============

__device__ __forceinline__ void accrow16(float* A, uint4 a, uint4 b) {
    float2 f;
    f = h2f(a.x); A[0]  += f.x; A[1]  += f.y;
    f = h2f(a.y); A[2]  += f.x; A[3]  += f.y;
    f = h2f(a.z); A[4]  += f.x; A[5]  += f.y;
    f = h2f(a.w); A[6]  += f.x; A[7]  += f.y;
    f = h2f(b.x); A[8]  += f.x; A[9]  += f.y;
    f = h2f(b.y); A[10] += f.x; A[11] += f.y;
    f = h2f(b.z); A[12] += f.x; A[13] += f.y;
    f = h2f(b.w); A[14] += f.x; A[15] += f.y;
}

__global__ __launch_bounds__(1024) void k_agg1(const unsigned int* __restrict__ bwords,
                                               const int* __restrict__ bucket_cursor,
                                               const __half* __restrict__ h1s,
                                               const float* __restrict__ b1, const float* __restrict__ W2,
                                               __half* __restrict__ h2s) {
    __shared__ int cnt[256];
    __shared__ int st[256];
    __shared__ unsigned int ew[WMAX];
    int b = blockIdx.x;
    int tid = threadIdx.x;
    int p0 = b * WMAX;
    int m = min(bucket_cursor[b], WMAX);

    if (tid < 256) cnt[tid] = 0;
    __syncthreads();
    for (int i = tid; i < m; i += 1024) atomicAdd(&cnt[bwords[p0 + i] >> 24], 1);
    __syncthreads();
    if (tid < 256) st[tid] = cnt[tid];
    __syncthreads();
    #pragma unroll
    for (int off = 1; off < 256; off <<= 1) {
        int t = 0;
        if (tid < 256 && tid >= off) t = st[tid - off];
        __syncthreads();
        if (tid < 256) st[tid] += t;
        __syncthreads();
    }
    if (tid < 256) { st[tid] -= cnt[tid]; cnt[tid] = 0; }   // st = exclusive start
    __syncthreads();
    for (int i = tid; i < m; i += 1024) {
        unsigned int w = bwords[p0 + i];        // L2-warm re-read
        int loc = w >> 24;
        int r = atomicAdd(&cnt[loc], 1);
        ew[st[loc] + r] = w & 0xFFFFFFu;        // pure src id, node-grouped
    }
    __syncthreads();

    int ln = tid >> 2;
    int sub = tid & 3;
    int n = (b << 8) + ln;
    int v = cnt[ln];
    int e0 = st[ln];
    int e1 = e0 + v;
    float acc[HID];
    #pragma unroll
    for (int c = 0; c < HID; ++c) acc[c] = 0.f;

    int j = e0 + sub;
    for (; j + 12 < e1; j += 16) {           // unroll 4: 8 rows' loads in flight per lane
        unsigned s0 = ew[j], s1 = ew[j + 4], s2 = ew[j + 8], s3 = ew[j + 12];
        const uint4* P0 = (const uint4*)(h1s + (size_t)s0 * HID);
        const uint4* P1 = (const uint4*)(h1s + (size_t)s1 * HID);
        const uint4* P2 = (const uint4*)(h1s + (size_t)s2 * HID);
        const uint4* P3 = (const uint4*)(h1s + (size_t)s3 * HID);
        uint4 a0 = P0[0], c0 = P0[1];
        uint4 a1 = P1[0], c1 = P1[1];
        uint4 a2 = P2[0], c2 = P2[1];
        uint4 a3 = P3[0], c3 = P3[1];
        accrow16(acc, a0, c0);
        accrow16(acc, a1, c1);
        accrow16(acc, a2, c2);
        accrow16(acc, a3, c3);
    }
    for (; j + 4 < e1; j += 8) {
        unsigned s0 = ew[j], s1 = ew[j + 4];
        const uint4* P0 = (const uint4*)(h1s + (size_t)s0 * HID);
        const uint4* P1 = (const uint4*)(h1s + (size_t)s1 * HID);
        uint4 a0 = P0[0], c0 = P0[1], a1 = P1[0], c1 = P1[1];
        accrow16(acc, a0, c0);
        accrow16(acc, a1, c1);
    }
    if (j < e1) {
        unsigned s0 = ew[j];
        const uint4* P0 = (const uint4*)(h1s + (size_t)s0 * HID);
        uint4 a0 = P0[0], c0 = P0[1];
        accrow16(acc, a0, c0);
    }
    #pragma unroll
    for (int c = 0; c < HID; ++c) {
        acc[c] += __shfl_xor(acc[c], 1);
        acc[c] += __shfl_xor(acc[c], 2);
    }
    if (sub == 0 && n < NN) {
        {   // self-loop from own (prescaled) row
            const uint4* q = (const uint4*)(h1s + (size_t)n * HID);
            uint4 a = q[0], bb = q[1];
            accrow16(acc, a, bb);
        }
        float dv = rsqrtf((float)(v + 1));      // identical to gemm1's dinv
        float h[HID];
        #pragma unroll
        for (int c = 0; c < HID; ++c) h[c] = fmaxf(fmaf(dv, acc[c], b1[c]), 0.f);
        float z[8];
        #pragma unroll
        for (int jj = 0; jj < NC; ++jj) {
            float t2 = 0.f;
            #pragma unroll
            for (int c = 0; c < HID; ++c) t2 = fmaf(h[c], W2[c * NC + jj], t2);
            z[jj] = t2 * dv;
        }
        z[7] = 0.f;
        uint4 u;
        u.x = f2h(z[0], z[1]); u.y = f2h(z[2], z[3]); u.z = f2h(z[4], z[5]); u.w = f2h(z[6], z[7]);
        *(uint4*)(h2s + (size_t)n * 8) = u;
    }
}

// ============ agg2: same fused structure, 16B rows, fp32 out (unroll-2 control) ============

__global__ __launch_bounds__(1024) void k_agg2(const unsigned int* __restrict__ bwords,
                                               const int* __restrict__ bucket_cursor,
                                               const __half* __restrict__ h2s,
                                               const float* __restrict__ b2, float* __restrict__ out) {
    __shared__ int cnt[256];
    __shared__ int st[256];
    __shared__ unsigned int ew[WMAX];
    int b = blockIdx.x;
    int tid = threadIdx.x;
    int p0 = b * WMAX;
    int m = min(bucket_cursor[b], WMAX);

    if (tid < 256) cnt[tid] = 0;
    __syncthreads();
    for (int i = tid; i < m; i += 1024) atomicAdd(&cnt[bwords[p0 + i] >> 24], 1);
    __syncthreads();
    if (tid < 256) st[tid] = cnt[tid];
    __syncthreads();
    #pragma unroll
    for (int off = 1; off < 256; off <<= 1) {
        int t = 0;
        if (tid < 256 && tid >= off) t = st[tid - off];
        __syncthreads();
        if (tid < 256) st[tid] += t;
        __syncthreads();
    }
    if (tid < 256) { st[tid] -= cnt[tid]; cnt[tid] = 0; }
    __syncthreads();
    for (int i = tid; i < m; i += 1024) {
        unsigned int w = bwords[p0 + i];
        int loc = w >> 24;
        int r = atomicAdd(&cnt[loc], 1);
        ew[st[loc] + r] = w & 0xFFFFFFu;
    }
    __syncthreads();

    int ln = tid >> 2;
    int sub = tid & 3;
    int n = (b << 8) + ln;
    int v = cnt[ln];
    int e0 = st[ln];
    int e1 = e0 + v;
    float A[8];
    #pragma unroll
    for (int c = 0; c < 8; ++c) A[c] = 0.f;

    int j = e0 + sub;
    for (; j + 4 < e1; j += 8) {
        unsigned s0 = ew[j], s1 = ew[j + 4];
        uint4 a = *(const uint4*)(h2s + (size_t)s0 * 8);
        uint4 c = *(const uint4*)(h2s + (size_t)s1 * 8);
        float2 f;
        f = h2f(a.x); A[0] += f.x; A[1] += f.y;
        f = h2f(a.y); A[2] += f.x; A[3] += f.y;
        f = h2f(a.z); A[4] += f.x; A[5] += f.y;
        f = h2f(a.w); A[6] += f.x;
        f = h2f(c.x); A[0] += f.x; A[1] += f.y;
        f = h2f(c.y); A[2] += f.x; A[3] += f.y;
        f = h2f(c.z); A[4] += f.x; A[5] += f.y;
        f = h2f(c.w); A[6] += f.x;
    }
    if (j < e1) {
        unsigned s0 = ew[j];
        uint4 a = *(const uint4*)(h2s + (size_t)s0 * 8);
        float2 f;
        f = h2f(a.x); A[0] += f.x; A[1] += f.y;
        f = h2f(a.y); A[2] += f.x; A[3] += f.y;
        f = h2f(a.z); A[4] += f.x; A[5] += f.y;
        f = h2f(a.w); A[6] += f.x;
    }
    #pragma unroll
    for (int c = 0; c < NC; ++c) {
        A[c] += __shfl_xor(A[c], 1);
        A[c] += __shfl_xor(A[c], 2);
    }
    if (sub == 0 && n < NN) {
        {   // self-loop
            uint4 a = *(const uint4*)(h2s + (size_t)n * 8);
            float2 f;
            f = h2f(a.x); A[0] += f.x; A[1] += f.y;
            f = h2f(a.y); A[2] += f.x; A[3] += f.y;
            f = h2f(a.z); A[4] += f.x; A[5] += f.y;
            f = h2f(a.w); A[6] += f.x;
        }
        float dv = rsqrtf((float)(v + 1));
        #pragma unroll
        for (int jj = 0; jj < NC; ++jj) out[(size_t)n * NC + jj] = fmaf(dv, A[jj], b2[jj]);
    }
}

// ============ launch ============

extern "C" void kernel_launch(void* const* d_in, const int* in_sizes, int n_in,
                              void* d_out, int out_size, void* d_ws, size_t ws_size,
                              hipStream_t stream) {
    const float* x  = (const float*)d_in[0];
    const int*   ei = (const int*)d_in[1];
    const float* W1 = (const float*)d_in[2];
    const float* b1 = (const float*)d_in[3];
    const float* W2 = (const float*)d_in[4];
    const float* b2 = (const float*)d_in[5];
    const int* src = ei;
    const int* dst = ei + NE;
    float* out = (float*)d_out;

    char* ws = (char*)d_ws;
    size_t o = 0;
    auto alloc = [&](size_t bytes) {
        char* p = ws + o;
        o = (o + bytes + 255) & ~(size_t)255;
        return p;
    };
    int*   bucket_cursor = (int*)alloc((size_t)(K + 1) * 4);
    unsigned int* bwords = (unsigned int*)alloc((size_t)K * WMAX * 4);   // 32 MB fixed regions
    __half* h1s  = (__half*)alloc((size_t)NN * HID * 2);
    __half* h2s  = (__half*)alloc((size_t)NN * 8 * 2);

    hipMemsetAsync(bucket_cursor, 0, (size_t)(K + 1) * 4, stream);
    k_bfill <<<EB, 256, 0, stream>>>(src, dst, bucket_cursor, bwords);
    k_gemm1 <<<NB, 256, 0, stream>>>(x, W1, bwords, bucket_cursor, h1s);
    k_agg1  <<<K, 1024, 0, stream>>>(bwords, bucket_cursor, h1s, b1, W2, h2s);
    k_agg2  <<<K, 1024, 0, stream>>>(bwords, bucket_cursor, h2s, b2, out);
}